// Round 6
// baseline (613.844 us; speedup 1.0000x reference)
//
#include <hip/hip_runtime.h>
#include <cstdint>
#include <cstddef>

// ---------------------------------------------------------------------------
// Transformer encoder block, bf16 MFMA implementation.
//   x:[2,4096,768] fp32 (+ fp32 weights) -> out fp32 [2,4096,768]
// R6: attention PV uses v_mfma_f32_16x16x16_bf16 (the _1k builtin) so P is
// consumed DIRECTLY from the S^T accumulator registers (C-layout of S^T ==
// B-layout of the K=16 MFMA). The entire P LDS round-trip (8 b64 writes +
// 4 b128 reads + lgkmcnt(0) drain per wave-iter) is eliminated. attn was
// measured DS-pipe-saturated (R3/R4/R5 all ~190us regardless of DS op count).
// ---------------------------------------------------------------------------

#define D_MODEL 768
#define N_HEADS 12
#define D_K     64
#define SEQ     4096
#define BATCH   2
#define M_ROWS  (BATCH * SEQ)   // 8192
#define H_FF    3072
#define LDQKV   2304            // packed QKV row pitch

typedef __bf16 bf16_t;
typedef __attribute__((ext_vector_type(8))) __bf16 bf16x8;
typedef __attribute__((ext_vector_type(4))) __bf16 bf16x4;
typedef __attribute__((ext_vector_type(2))) __bf16 bf16x2;
typedef __attribute__((ext_vector_type(4))) float  floatx4;
typedef __attribute__((ext_vector_type(4))) short  short4_t;

union bf16x4_cast { bf16x4 h; short4_t s; };

__device__ __forceinline__ float gelu_exact(float x) {
    return 0.5f * x * (1.0f + erff(x * 0.70710678118654752f));
}

// async global->LDS, 16B per lane, dest = wave-uniform base + lane*16
#define GLL16(gp, lp)                                                         \
    __builtin_amdgcn_global_load_lds(                                         \
        (const __attribute__((address_space(1))) void*)(gp),                  \
        (__attribute__((address_space(3))) void*)(lp), 16, 0, 0)

// -------------------------------- convert ----------------------------------
__global__ __launch_bounds__(256) void f32_to_bf16_scale_kernel(
    const float* __restrict__ src, bf16_t* __restrict__ dst, int n, float scale) {
    int i = blockIdx.x * 256 + threadIdx.x;
    if (i < n) dst[i] = (bf16_t)(src[i] * scale);
}

__global__ __launch_bounds__(256) void pack_bias_kernel(
    const float* __restrict__ bq, const float* __restrict__ bk,
    const float* __restrict__ bv, float* __restrict__ dst) {
    int i = blockIdx.x * 256 + threadIdx.x;
    if (i < 768)       dst[i] = bq[i] * 0.125f;
    else if (i < 1536) dst[i] = bk[i - 768];
    else if (i < 2304) dst[i] = bv[i - 1536];
}

// -------------------------------- GEMM -------------------------------------
// C[m,n] = act( sum_k A[m,k]*W[n,k] + bias[n] ). m97 structure: 128xBN tile,
// BK=32, global_load_lds w16 staging, LDS [row][k] pitch 32.
template<int BN>   // 128 or 64
__global__ __launch_bounds__(256) void gemm_lds_kernel(
    const bf16_t* __restrict__ A, const bf16_t* __restrict__ W,
    const float* __restrict__ bias, bf16_t* __restrict__ C,
    int M, int N, int K, int act) {

    __shared__ bf16_t As[128 * 32];
    __shared__ bf16_t Bs[BN * 32];

    const int t    = threadIdx.x;
    const int lane = t & 63;
    const int w    = t >> 6;
    const int lrow = lane & 15;
    const int quad = lane >> 4;
    const int n0   = blockIdx.x * BN;
    const int m0   = blockIdx.y * 128;

    constexpr int MI  = (BN == 128) ? 4 : 2;
    const int wmo = (BN == 128) ? (w >> 1) * 64 : w * 32;
    const int wno = (BN == 128) ? (w & 1) * 64 : 0;

    const int aidx0 = (w * 2 + 0) * 64 + lane;
    const int aidx1 = (w * 2 + 1) * 64 + lane;
    const size_t a_g0 = (size_t)(m0 + (aidx0 >> 2)) * K + (aidx0 & 3) * 8;
    const size_t a_g1 = (size_t)(m0 + (aidx1 >> 2)) * K + (aidx1 & 3) * 8;
    size_t b_g0, b_g1 = 0;
    if constexpr (BN == 128) {
        b_g0 = (size_t)(n0 + (aidx0 >> 2)) * K + (aidx0 & 3) * 8;
        b_g1 = (size_t)(n0 + (aidx1 >> 2)) * K + (aidx1 & 3) * 8;
    } else {
        const int bidx = w * 64 + lane;
        b_g0 = (size_t)(n0 + (bidx >> 2)) * K + (bidx & 3) * 8;
    }

    floatx4 acc[MI][4];
#pragma unroll
    for (int i = 0; i < MI; ++i)
#pragma unroll
        for (int j = 0; j < 4; ++j) acc[i][j] = floatx4{0.f, 0.f, 0.f, 0.f};

    for (int k0 = 0; k0 < K; k0 += 32) {
        GLL16(&A[a_g0 + k0], &As[(w * 2 + 0) * 512]);
        GLL16(&A[a_g1 + k0], &As[(w * 2 + 1) * 512]);
        if constexpr (BN == 128) {
            GLL16(&W[b_g0 + k0], &Bs[(w * 2 + 0) * 512]);
            GLL16(&W[b_g1 + k0], &Bs[(w * 2 + 1) * 512]);
        } else {
            GLL16(&W[b_g0 + k0], &Bs[w * 512]);
        }
        __syncthreads();

        bf16x8 a[MI], b[4];
#pragma unroll
        for (int i = 0; i < MI; ++i)
            a[i] = *(bf16x8*)&As[(wmo + i * 16 + lrow) * 32 + quad * 8];
#pragma unroll
        for (int j = 0; j < 4; ++j)
            b[j] = *(bf16x8*)&Bs[(wno + j * 16 + lrow) * 32 + quad * 8];
#pragma unroll
        for (int i = 0; i < MI; ++i)
#pragma unroll
            for (int j = 0; j < 4; ++j)
                acc[i][j] = __builtin_amdgcn_mfma_f32_16x16x32_bf16(a[i], b[j], acc[i][j], 0, 0, 0);
        __syncthreads();
    }

#pragma unroll
    for (int i = 0; i < MI; ++i) {
#pragma unroll
        for (int j = 0; j < 4; ++j) {
            const int n = n0 + wno + j * 16 + lrow;
            const float bv = bias[n];
#pragma unroll
            for (int r = 0; r < 4; ++r) {
                const int m = m0 + wmo + i * 16 + quad * 4 + r;
                float v = acc[i][j][r] + bv;
                if (act) v = gelu_exact(v);
                C[(size_t)m * N + n] = (bf16_t)v;
            }
        }
    }
}

// ------------------------------ attention ----------------------------------
// Flash-style, fixed-base softmax, deferred row-sum.
//   S^T = K*Q^T   (k32 MFMA; C-layout: lane holds q=lrow, keys=quad*4+r)
//   P = exp(S^T) stays in registers; consumed as the B operand of
//   O^T = V^T*P^T (k16 MFMA; B-layout: lane holds n=lrow, k=quad*4+i) -- the
//   layouts match exactly, so no LDS round-trip for P.
//   O^T C-layout: lane holds q=lrow, d=16dt+quad*4+r -> b64 packed stores,
//   and l-normalization needs no cross-lane redistribution.
__global__ __launch_bounds__(256, 3) void attn_kernel(
    const bf16_t* __restrict__ QKV, bf16_t* __restrict__ Ctx) {

    __shared__ bf16_t Ks[64 * 72];        // 9216 B  [key][d] pitch 72
    __shared__ bf16_t Vt[64 * 64];        // 8192 B  [d][key^vsw(d)]

    const int t    = threadIdx.x;
    const int lane = t & 63;
    const int w    = t >> 6;
    const int lrow = lane & 15;
    const int quad = lane >> 4;

    const int b  = blockIdx.y / N_HEADS;
    const int h  = blockIdx.y % N_HEADS;
    const int q0 = blockIdx.x * 128 + w * 32;
    const size_t base_q = ((size_t)b * SEQ) * LDQKV + h * D_K;
    const size_t base_k = base_q + 768;
    const size_t base_v = base_q + 1536;
    const size_t base_o = ((size_t)b * SEQ) * D_MODEL + h * D_K;

    // Q fragments (B operand of S^T = K*Q^T: n=q=lane&15, k=d).
    bf16x8 qf[2][2];
#pragma unroll
    for (int s = 0; s < 2; ++s) {
        const size_t qrow = base_q + (size_t)(q0 + s * 16 + lrow) * LDQKV + quad * 8;
        qf[s][0] = *(const bf16x8*)&QKV[qrow];
        qf[s][1] = *(const bf16x8*)&QKV[qrow + 32];
    }

    float l_part[2] = {0.f, 0.f};
    floatx4 o_acc[2][4];
#pragma unroll
    for (int s = 0; s < 2; ++s)
#pragma unroll
        for (int d = 0; d < 4; ++d) o_acc[s][d] = floatx4{0.f, 0.f, 0.f, 0.f};

    // staging assignments
    const int skey = t >> 2;                       // Ks: key 0..63
    const int sch  = t & 3;                        //     d-chunk 0..3
    const int kp   = t >> 3;                       // Vt: key pair 0..31
    const int sch8 = t & 7;                        //     d-chunk-of-8 0..7
    const int vsw  = ((sch8 & 1) << 5) | ((sch8 & 2) << 3);  // Vt write swizzle

    for (int k0 = 0; k0 < SEQ; k0 += 64) {
        // ---- stage K[64][72] ----
        const size_t gk = base_k + (size_t)(k0 + skey) * LDQKV + sch * 8;
        bf16x8 kv0 = *(const bf16x8*)&QKV[gk];
        bf16x8 kv1 = *(const bf16x8*)&QKV[gk + 32];
        *(bf16x8*)&Ks[skey * 72 + sch * 8]      = kv0;
        *(bf16x8*)&Ks[skey * 72 + sch * 8 + 32] = kv1;
        // ---- stage swizzled V^T[64][64], 2 keys/thread, packed b32 writes --
        const size_t gv = base_v + (size_t)(k0 + 2 * kp) * LDQKV + sch8 * 8;
        bf16x8 vv0 = *(const bf16x8*)&QKV[gv];
        bf16x8 vv1 = *(const bf16x8*)&QKV[gv + LDQKV];
        const int vcol = (2 * kp) ^ vsw;
#pragma unroll
        for (int j = 0; j < 8; ++j)
            *(bf16x2*)&Vt[(sch8 * 8 + j) * 64 + vcol] = bf16x2{vv0[j], vv1[j]};
        __syncthreads();

        // ---- S^T = K Q^T (k32), exp -> P kept in registers ----
        short4_t p[2][4];
#pragma unroll
        for (int kt = 0; kt < 4; ++kt) {
            bf16x8 ka0 = *(bf16x8*)&Ks[(kt * 16 + lrow) * 72 + quad * 8];
            bf16x8 ka1 = *(bf16x8*)&Ks[(kt * 16 + lrow) * 72 + 32 + quad * 8];
            floatx4 z = floatx4{0.f, 0.f, 0.f, 0.f};
#pragma unroll
            for (int s = 0; s < 2; ++s) {
                floatx4 st = __builtin_amdgcn_mfma_f32_16x16x32_bf16(ka0, qf[s][0], z, 0, 0, 0);
                st = __builtin_amdgcn_mfma_f32_16x16x32_bf16(ka1, qf[s][1], st, 0, 0, 0);
                float p0 = __expf(st[0]), p1 = __expf(st[1]);
                float p2 = __expf(st[2]), p3 = __expf(st[3]);
                l_part[s] += (p0 + p1) + (p2 + p3);
                bf16x4_cast pc;
                pc.h = bf16x4{(bf16_t)p0, (bf16_t)p1, (bf16_t)p2, (bf16_t)p3};
                p[s][kt] = pc.s;
            }
        }

        // ---- O^T += V^T P^T (k16): A = V^T b64 frag, B = P from registers --
#pragma unroll
        for (int dt = 0; dt < 4; ++dt) {
            const int d = dt * 16 + lrow;
            const int swv = ((lrow & 8) << 2) | ((dt & 1) << 4);   // == vsw(d)
#pragma unroll
            for (int kc = 0; kc < 4; ++kc) {
                bf16x4_cast ac;
                ac.h = *(bf16x4*)&Vt[d * 64 + ((kc * 16 + quad * 4) ^ swv)];
                o_acc[0][dt] = __builtin_amdgcn_mfma_f32_16x16x16bf16_1k(
                    ac.s, p[0][kc], o_acc[0][dt], 0, 0, 0);
                o_acc[1][dt] = __builtin_amdgcn_mfma_f32_16x16x16bf16_1k(
                    ac.s, p[1][kc], o_acc[1][dt], 0, 0, 0);
            }
        }
        __syncthreads();   // protect Ks/Vt before next staging
    }

    // ---- reduce l across quads + normalize + packed b64 stores ----
    // O^T C-layout: lane holds q = lrow (matches l), d = 16dt + 4quad + r.
#pragma unroll
    for (int s = 0; s < 2; ++s) {
        float lsum = l_part[s];
        lsum += __shfl_xor(lsum, 16, 64);
        lsum += __shfl_xor(lsum, 32, 64);
        const float inv = 1.0f / lsum;
        const size_t orow = base_o + (size_t)(q0 + s * 16 + lrow) * D_MODEL;
#pragma unroll
        for (int dt = 0; dt < 4; ++dt) {
            bf16x4 ov = bf16x4{(bf16_t)(o_acc[s][dt][0] * inv),
                               (bf16_t)(o_acc[s][dt][1] * inv),
                               (bf16_t)(o_acc[s][dt][2] * inv),
                               (bf16_t)(o_acc[s][dt][3] * inv)};
            *(bf16x4*)&Ctx[orow + dt * 16 + quad * 4] = ov;
        }
    }
}

// --------------------------- residual + layernorm --------------------------
__global__ __launch_bounds__(256) void ln_res_f32in_kernel(
    const float* __restrict__ x, const bf16_t* __restrict__ res,
    const float* __restrict__ g, const float* __restrict__ be,
    bf16_t* __restrict__ out) {
    const int row = blockIdx.x, t = threadIdx.x;
    const size_t base = (size_t)row * D_MODEL;
    float vals[3], sum = 0.f, sq = 0.f;
#pragma unroll
    for (int it = 0; it < 3; ++it) {
        int i = t + it * 256;
        float v = x[base + i] + (float)res[base + i];
        vals[it] = v; sum += v; sq += v * v;
    }
#pragma unroll
    for (int d = 1; d < 64; d <<= 1) { sum += __shfl_xor(sum, d, 64); sq += __shfl_xor(sq, d, 64); }
    __shared__ float ssum[4], ssq[4], s_mu, s_rs;
    if ((t & 63) == 0) { ssum[t >> 6] = sum; ssq[t >> 6] = sq; }
    __syncthreads();
    if (t == 0) {
        float S = ssum[0] + ssum[1] + ssum[2] + ssum[3];
        float Qq = ssq[0] + ssq[1] + ssq[2] + ssq[3];
        float mu = S / D_MODEL;
        s_mu = mu;
        s_rs = rsqrtf(Qq / D_MODEL - mu * mu + 1e-5f);
    }
    __syncthreads();
    const float mu = s_mu, rs = s_rs;
#pragma unroll
    for (int it = 0; it < 3; ++it) {
        int i = t + it * 256;
        out[base + i] = (bf16_t)((vals[it] - mu) * rs * g[i] + be[i]);
    }
}

__global__ __launch_bounds__(256) void ln_res_final_kernel(
    const bf16_t* __restrict__ a, const bf16_t* __restrict__ bfb,
    const float* __restrict__ g, const float* __restrict__ be,
    float* __restrict__ out) {
    const int row = blockIdx.x, t = threadIdx.x;
    const size_t base = (size_t)row * D_MODEL;
    float vals[3], sum = 0.f, sq = 0.f;
#pragma unroll
    for (int it = 0; it < 3; ++it) {
        int i = t + it * 256;
        float v = (float)a[base + i] + (float)bfb[base + i];
        vals[it] = v; sum += v; sq += v * v;
    }
#pragma unroll
    for (int d = 1; d < 64; d <<= 1) { sum += __shfl_xor(sum, d, 64); sq += __shfl_xor(sq, d, 64); }
    __shared__ float ssum[4], ssq[4], s_mu, s_rs;
    if ((t & 63) == 0) { ssum[t >> 6] = sum; ssq[t >> 6] = sq; }
    __syncthreads();
    if (t == 0) {
        float S = ssum[0] + ssum[1] + ssum[2] + ssum[3];
        float Qq = ssq[0] + ssq[1] + ssq[2] + ssq[3];
        float mu = S / D_MODEL;
        s_mu = mu;
        s_rs = rsqrtf(Qq / D_MODEL - mu * mu + 1e-5f);
    }
    __syncthreads();
    const float mu = s_mu, rs = s_rs;
#pragma unroll
    for (int it = 0; it < 3; ++it) {
        int i = t + it * 256;
        out[base + i] = (vals[it] - mu) * rs * g[i] + be[i];
    }
}

// ------------------------------- launcher ----------------------------------
extern "C" void kernel_launch(void* const* d_in, const int* in_sizes, int n_in,
                              void* d_out, int out_size, void* d_ws, size_t ws_size,
                              hipStream_t stream) {
    const float* x    = (const float*)d_in[0];
    const float* wq   = (const float*)d_in[1];
    const float* bq   = (const float*)d_in[2];
    const float* wk   = (const float*)d_in[3];
    const float* bk   = (const float*)d_in[4];
    const float* wv   = (const float*)d_in[5];
    const float* bv   = (const float*)d_in[6];
    const float* wo   = (const float*)d_in[7];
    const float* bo   = (const float*)d_in[8];
    const float* w1   = (const float*)d_in[9];
    const float* b1   = (const float*)d_in[10];
    const float* w2   = (const float*)d_in[11];
    const float* b2   = (const float*)d_in[12];
    const float* g1   = (const float*)d_in[13];
    const float* be1  = (const float*)d_in[14];
    const float* g2   = (const float*)d_in[15];
    const float* be2  = (const float*)d_in[16];
    float* out = (float*)d_out;

    // ---- workspace layout (aliased; ~127.5 MB) ----
    char* ws = (char*)d_ws;
    const size_t SZ_XB   = (size_t)M_ROWS * D_MODEL * 2;
    const size_t SZ_QKV  = (size_t)M_ROWS * LDQKV * 2;
    const size_t SZ_CTX  = SZ_XB;
    const size_t SZ_H    = (size_t)M_ROWS * H_FF * 2;
    const size_t SZ_WQKV = (size_t)LDQKV * D_MODEL * 2;
    const size_t SZ_WO   = (size_t)D_MODEL * D_MODEL * 2;
    const size_t SZ_W1   = (size_t)H_FF * D_MODEL * 2;

    bf16_t* xb    = (bf16_t*)(ws);                    // also n1 after LN1
    bf16_t* qkvb  = (bf16_t*)(ws + SZ_XB);            // also mha out (reuse)
    bf16_t* ctxb  = (bf16_t*)(ws + SZ_XB + SZ_QKV);   // also ffn2 out (reuse)
    bf16_t* hb    = (bf16_t*)(ws + SZ_XB + SZ_QKV + SZ_CTX);
    char*   wsw   = ws + SZ_XB + SZ_QKV + SZ_CTX + SZ_H;
    bf16_t* wqkvb = (bf16_t*)(wsw);
    bf16_t* wob   = (bf16_t*)(wsw + SZ_WQKV);
    bf16_t* w1b   = (bf16_t*)(wsw + SZ_WQKV + SZ_WO);
    bf16_t* w2b   = (bf16_t*)(wsw + SZ_WQKV + SZ_WO + SZ_W1);
    float*  bqkv  = (float*)(wsw + SZ_WQKV + SZ_WO + 2 * SZ_W1);
    bf16_t* mhab  = qkvb;
    bf16_t* n1b   = xb;
    bf16_t* ffb   = ctxb;

    const int n_x = M_ROWS * D_MODEL;
    const int n_w = D_MODEL * D_MODEL;
    const int n_wf = H_FF * D_MODEL;

    f32_to_bf16_scale_kernel<<<(n_x + 255) / 256, 256, 0, stream>>>(x, xb, n_x, 1.0f);
    f32_to_bf16_scale_kernel<<<(n_w + 255) / 256, 256, 0, stream>>>(wq, wqkvb, n_w, 0.125f);
    f32_to_bf16_scale_kernel<<<(n_w + 255) / 256, 256, 0, stream>>>(wk, wqkvb + (size_t)768 * 768, n_w, 1.0f);
    f32_to_bf16_scale_kernel<<<(n_w + 255) / 256, 256, 0, stream>>>(wv, wqkvb + (size_t)1536 * 768, n_w, 1.0f);
    f32_to_bf16_scale_kernel<<<(n_w + 255) / 256, 256, 0, stream>>>(wo, wob, n_w, 1.0f);
    f32_to_bf16_scale_kernel<<<(n_wf + 255) / 256, 256, 0, stream>>>(w1, w1b, n_wf, 1.0f);
    f32_to_bf16_scale_kernel<<<(n_wf + 255) / 256, 256, 0, stream>>>(w2, w2b, n_wf, 1.0f);
    pack_bias_kernel<<<9, 256, 0, stream>>>(bq, bk, bv, bqkv);

    gemm_lds_kernel<128><<<dim3(LDQKV / 128, M_ROWS / 128), 256, 0, stream>>>(
        xb, wqkvb, bqkv, qkvb, M_ROWS, LDQKV, D_MODEL, 0);

    attn_kernel<<<dim3(SEQ / 128, BATCH * N_HEADS), 256, 0, stream>>>(qkvb, ctxb);

    gemm_lds_kernel<64><<<dim3(D_MODEL / 64, M_ROWS / 128), 256, 0, stream>>>(
        ctxb, wob, bo, mhab, M_ROWS, D_MODEL, D_MODEL, 0);

    ln_res_f32in_kernel<<<M_ROWS, 256, 0, stream>>>(x, mhab, g1, be1, n1b);

    gemm_lds_kernel<128><<<dim3(H_FF / 128, M_ROWS / 128), 256, 0, stream>>>(
        n1b, w1b, b1, hb, M_ROWS, H_FF, D_MODEL, 1);

    gemm_lds_kernel<64><<<dim3(D_MODEL / 64, M_ROWS / 128), 256, 0, stream>>>(
        hb, w2b, b2, ffb, M_ROWS, D_MODEL, H_FF, 0);

    ln_res_final_kernel<<<M_ROWS, 256, 0, stream>>>(n1b, ffb, g2, be2, out);
}

// Round 7
// 541.111 us; speedup vs baseline: 1.1344x; 1.1344x over previous
//
#include <hip/hip_runtime.h>
#include <cstdint>
#include <cstddef>

// ---------------------------------------------------------------------------
// Transformer encoder block, bf16 MFMA implementation.
//   x:[2,4096,768] fp32 (+ fp32 weights) -> out fp32 [2,4096,768]
// R7: R6 (register-P via k16 PV MFMA) + Vt bank-geometry fix: pitch 64->72
// (row stride 36 dwords == 4 banks mod 32, making the row visible to the
// bank index) + xor swizzle col^=((d>>3)&7)<<3. Derived: reads AND writes
// both land at 2-way aliasing (free, phase floor). R6's 8-way Vt-read
// conflict (1.007e8 cycles) was the measured regression mechanism.
// ---------------------------------------------------------------------------

#define D_MODEL 768
#define N_HEADS 12
#define D_K     64
#define SEQ     4096
#define BATCH   2
#define M_ROWS  (BATCH * SEQ)   // 8192
#define H_FF    3072
#define LDQKV   2304            // packed QKV row pitch

typedef __bf16 bf16_t;
typedef __attribute__((ext_vector_type(8))) __bf16 bf16x8;
typedef __attribute__((ext_vector_type(4))) __bf16 bf16x4;
typedef __attribute__((ext_vector_type(2))) __bf16 bf16x2;
typedef __attribute__((ext_vector_type(4))) float  floatx4;
typedef __attribute__((ext_vector_type(4))) short  short4_t;

union bf16x4_cast { bf16x4 h; short4_t s; };

__device__ __forceinline__ float gelu_exact(float x) {
    return 0.5f * x * (1.0f + erff(x * 0.70710678118654752f));
}

// async global->LDS, 16B per lane, dest = wave-uniform base + lane*16
#define GLL16(gp, lp)                                                         \
    __builtin_amdgcn_global_load_lds(                                         \
        (const __attribute__((address_space(1))) void*)(gp),                  \
        (__attribute__((address_space(3))) void*)(lp), 16, 0, 0)

// -------------------------------- convert ----------------------------------
__global__ __launch_bounds__(256) void f32_to_bf16_scale_kernel(
    const float* __restrict__ src, bf16_t* __restrict__ dst, int n, float scale) {
    int i = blockIdx.x * 256 + threadIdx.x;
    if (i < n) dst[i] = (bf16_t)(src[i] * scale);
}

__global__ __launch_bounds__(256) void pack_bias_kernel(
    const float* __restrict__ bq, const float* __restrict__ bk,
    const float* __restrict__ bv, float* __restrict__ dst) {
    int i = blockIdx.x * 256 + threadIdx.x;
    if (i < 768)       dst[i] = bq[i] * 0.125f;
    else if (i < 1536) dst[i] = bk[i - 768];
    else if (i < 2304) dst[i] = bv[i - 1536];
}

// -------------------------------- GEMM -------------------------------------
// C[m,n] = act( sum_k A[m,k]*W[n,k] + bias[n] ). m97 structure: 128xBN tile,
// BK=32, global_load_lds w16 staging, LDS [row][k] pitch 32.
template<int BN>   // 128 or 64
__global__ __launch_bounds__(256) void gemm_lds_kernel(
    const bf16_t* __restrict__ A, const bf16_t* __restrict__ W,
    const float* __restrict__ bias, bf16_t* __restrict__ C,
    int M, int N, int K, int act) {

    __shared__ bf16_t As[128 * 32];
    __shared__ bf16_t Bs[BN * 32];

    const int t    = threadIdx.x;
    const int lane = t & 63;
    const int w    = t >> 6;
    const int lrow = lane & 15;
    const int quad = lane >> 4;
    const int n0   = blockIdx.x * BN;
    const int m0   = blockIdx.y * 128;

    constexpr int MI  = (BN == 128) ? 4 : 2;
    const int wmo = (BN == 128) ? (w >> 1) * 64 : w * 32;
    const int wno = (BN == 128) ? (w & 1) * 64 : 0;

    const int aidx0 = (w * 2 + 0) * 64 + lane;
    const int aidx1 = (w * 2 + 1) * 64 + lane;
    const size_t a_g0 = (size_t)(m0 + (aidx0 >> 2)) * K + (aidx0 & 3) * 8;
    const size_t a_g1 = (size_t)(m0 + (aidx1 >> 2)) * K + (aidx1 & 3) * 8;
    size_t b_g0, b_g1 = 0;
    if constexpr (BN == 128) {
        b_g0 = (size_t)(n0 + (aidx0 >> 2)) * K + (aidx0 & 3) * 8;
        b_g1 = (size_t)(n0 + (aidx1 >> 2)) * K + (aidx1 & 3) * 8;
    } else {
        const int bidx = w * 64 + lane;
        b_g0 = (size_t)(n0 + (bidx >> 2)) * K + (bidx & 3) * 8;
    }

    floatx4 acc[MI][4];
#pragma unroll
    for (int i = 0; i < MI; ++i)
#pragma unroll
        for (int j = 0; j < 4; ++j) acc[i][j] = floatx4{0.f, 0.f, 0.f, 0.f};

    for (int k0 = 0; k0 < K; k0 += 32) {
        GLL16(&A[a_g0 + k0], &As[(w * 2 + 0) * 512]);
        GLL16(&A[a_g1 + k0], &As[(w * 2 + 1) * 512]);
        if constexpr (BN == 128) {
            GLL16(&W[b_g0 + k0], &Bs[(w * 2 + 0) * 512]);
            GLL16(&W[b_g1 + k0], &Bs[(w * 2 + 1) * 512]);
        } else {
            GLL16(&W[b_g0 + k0], &Bs[w * 512]);
        }
        __syncthreads();

        bf16x8 a[MI], b[4];
#pragma unroll
        for (int i = 0; i < MI; ++i)
            a[i] = *(bf16x8*)&As[(wmo + i * 16 + lrow) * 32 + quad * 8];
#pragma unroll
        for (int j = 0; j < 4; ++j)
            b[j] = *(bf16x8*)&Bs[(wno + j * 16 + lrow) * 32 + quad * 8];
#pragma unroll
        for (int i = 0; i < MI; ++i)
#pragma unroll
            for (int j = 0; j < 4; ++j)
                acc[i][j] = __builtin_amdgcn_mfma_f32_16x16x32_bf16(a[i], b[j], acc[i][j], 0, 0, 0);
        __syncthreads();
    }

#pragma unroll
    for (int i = 0; i < MI; ++i) {
#pragma unroll
        for (int j = 0; j < 4; ++j) {
            const int n = n0 + wno + j * 16 + lrow;
            const float bv = bias[n];
#pragma unroll
            for (int r = 0; r < 4; ++r) {
                const int m = m0 + wmo + i * 16 + quad * 4 + r;
                float v = acc[i][j][r] + bv;
                if (act) v = gelu_exact(v);
                C[(size_t)m * N + n] = (bf16_t)v;
            }
        }
    }
}

// ------------------------------ attention ----------------------------------
// Flash-style, fixed-base softmax, deferred row-sum.
//   S^T = K*Q^T   (k32 MFMA; C-layout: lane holds q=lrow, keys=quad*4+r)
//   P = exp(S^T) stays in registers; consumed as the B operand of
//   O^T = V^T*P^T (k16 MFMA) -- layouts match exactly, no LDS trip for P.
// Vt layout: [d][key ^ (((d>>3)&7)<<3)], pitch 72. Row stride 36 dwords
// == 4 banks mod 32 puts d&7 into the bank index; the xor puts d>>3 in.
// Derived: b32 staging writes 2-way, b64 fragment reads 2-way (both free).
__global__ __launch_bounds__(256, 3) void attn_kernel(
    const bf16_t* __restrict__ QKV, bf16_t* __restrict__ Ctx) {

    __shared__ bf16_t Ks[64 * 72];        // 9216 B  [key][d] pitch 72
    __shared__ bf16_t Vt[64 * 72];        // 9216 B  [d][key^vsw(d)] pitch 72

    const int t    = threadIdx.x;
    const int lane = t & 63;
    const int w    = t >> 6;
    const int lrow = lane & 15;
    const int quad = lane >> 4;

    const int b  = blockIdx.y / N_HEADS;
    const int h  = blockIdx.y % N_HEADS;
    const int q0 = blockIdx.x * 128 + w * 32;
    const size_t base_q = ((size_t)b * SEQ) * LDQKV + h * D_K;
    const size_t base_k = base_q + 768;
    const size_t base_v = base_q + 1536;
    const size_t base_o = ((size_t)b * SEQ) * D_MODEL + h * D_K;

    // Q fragments (B operand of S^T = K*Q^T: n=q=lane&15, k=d).
    bf16x8 qf[2][2];
#pragma unroll
    for (int s = 0; s < 2; ++s) {
        const size_t qrow = base_q + (size_t)(q0 + s * 16 + lrow) * LDQKV + quad * 8;
        qf[s][0] = *(const bf16x8*)&QKV[qrow];
        qf[s][1] = *(const bf16x8*)&QKV[qrow + 32];
    }

    float l_part[2] = {0.f, 0.f};
    floatx4 o_acc[2][4];
#pragma unroll
    for (int s = 0; s < 2; ++s)
#pragma unroll
        for (int d = 0; d < 4; ++d) o_acc[s][d] = floatx4{0.f, 0.f, 0.f, 0.f};

    // staging assignments
    const int skey = t >> 2;                       // Ks: key 0..63
    const int sch  = t & 3;                        //     d-chunk 0..3
    const int kp   = t >> 3;                       // Vt: key pair 0..31
    const int sch8 = t & 7;                        //     d-chunk-of-8 0..7

    for (int k0 = 0; k0 < SEQ; k0 += 64) {
        // ---- stage K[64][72] ----
        const size_t gk = base_k + (size_t)(k0 + skey) * LDQKV + sch * 8;
        bf16x8 kv0 = *(const bf16x8*)&QKV[gk];
        bf16x8 kv1 = *(const bf16x8*)&QKV[gk + 32];
        *(bf16x8*)&Ks[skey * 72 + sch * 8]      = kv0;
        *(bf16x8*)&Ks[skey * 72 + sch * 8 + 32] = kv1;
        // ---- stage swizzled V^T[64][72], 2 keys/thread, packed b32 writes --
        // row d = sch8*8 + j; col = (2*kp) ^ (((d>>3)&7)<<3) = (2*kp)^(sch8<<3)
        const size_t gv = base_v + (size_t)(k0 + 2 * kp) * LDQKV + sch8 * 8;
        bf16x8 vv0 = *(const bf16x8*)&QKV[gv];
        bf16x8 vv1 = *(const bf16x8*)&QKV[gv + LDQKV];
        const int vcol = ((2 * kp) & 63) ^ (sch8 << 3);
#pragma unroll
        for (int j = 0; j < 8; ++j)
            *(bf16x2*)&Vt[(sch8 * 8 + j) * 72 + vcol] = bf16x2{vv0[j], vv1[j]};
        __syncthreads();

        // ---- S^T = K Q^T (k32), exp -> P kept in registers ----
        short4_t p[2][4];
#pragma unroll
        for (int kt = 0; kt < 4; ++kt) {
            bf16x8 ka0 = *(bf16x8*)&Ks[(kt * 16 + lrow) * 72 + quad * 8];
            bf16x8 ka1 = *(bf16x8*)&Ks[(kt * 16 + lrow) * 72 + 32 + quad * 8];
            floatx4 z = floatx4{0.f, 0.f, 0.f, 0.f};
#pragma unroll
            for (int s = 0; s < 2; ++s) {
                floatx4 st = __builtin_amdgcn_mfma_f32_16x16x32_bf16(ka0, qf[s][0], z, 0, 0, 0);
                st = __builtin_amdgcn_mfma_f32_16x16x32_bf16(ka1, qf[s][1], st, 0, 0, 0);
                float p0 = __expf(st[0]), p1 = __expf(st[1]);
                float p2 = __expf(st[2]), p3 = __expf(st[3]);
                l_part[s] += (p0 + p1) + (p2 + p3);
                bf16x4_cast pc;
                pc.h = bf16x4{(bf16_t)p0, (bf16_t)p1, (bf16_t)p2, (bf16_t)p3};
                p[s][kt] = pc.s;
            }
        }

        // ---- O^T += V^T P^T (k16): A = V^T b64 frag, B = P from registers --
#pragma unroll
        for (int dt = 0; dt < 4; ++dt) {
            const int d   = dt * 16 + lrow;
            const int swv = ((d >> 3) & 7) << 3;
#pragma unroll
            for (int kc = 0; kc < 4; ++kc) {
                bf16x4_cast ac;
                ac.h = *(bf16x4*)&Vt[d * 72 + ((kc * 16 + quad * 4) ^ swv)];
                o_acc[0][dt] = __builtin_amdgcn_mfma_f32_16x16x16bf16_1k(
                    ac.s, p[0][kc], o_acc[0][dt], 0, 0, 0);
                o_acc[1][dt] = __builtin_amdgcn_mfma_f32_16x16x16bf16_1k(
                    ac.s, p[1][kc], o_acc[1][dt], 0, 0, 0);
            }
        }
        __syncthreads();   // protect Ks/Vt before next staging
    }

    // ---- reduce l across quads + normalize + packed b64 stores ----
    // O^T C-layout: lane holds q = lrow (matches l), d = 16dt + 4quad + r.
#pragma unroll
    for (int s = 0; s < 2; ++s) {
        float lsum = l_part[s];
        lsum += __shfl_xor(lsum, 16, 64);
        lsum += __shfl_xor(lsum, 32, 64);
        const float inv = 1.0f / lsum;
        const size_t orow = base_o + (size_t)(q0 + s * 16 + lrow) * D_MODEL;
#pragma unroll
        for (int dt = 0; dt < 4; ++dt) {
            bf16x4 ov = bf16x4{(bf16_t)(o_acc[s][dt][0] * inv),
                               (bf16_t)(o_acc[s][dt][1] * inv),
                               (bf16_t)(o_acc[s][dt][2] * inv),
                               (bf16_t)(o_acc[s][dt][3] * inv)};
            *(bf16x4*)&Ctx[orow + dt * 16 + quad * 4] = ov;
        }
    }
}

// --------------------------- residual + layernorm --------------------------
__global__ __launch_bounds__(256) void ln_res_f32in_kernel(
    const float* __restrict__ x, const bf16_t* __restrict__ res,
    const float* __restrict__ g, const float* __restrict__ be,
    bf16_t* __restrict__ out) {
    const int row = blockIdx.x, t = threadIdx.x;
    const size_t base = (size_t)row * D_MODEL;
    float vals[3], sum = 0.f, sq = 0.f;
#pragma unroll
    for (int it = 0; it < 3; ++it) {
        int i = t + it * 256;
        float v = x[base + i] + (float)res[base + i];
        vals[it] = v; sum += v; sq += v * v;
    }
#pragma unroll
    for (int d = 1; d < 64; d <<= 1) { sum += __shfl_xor(sum, d, 64); sq += __shfl_xor(sq, d, 64); }
    __shared__ float ssum[4], ssq[4], s_mu, s_rs;
    if ((t & 63) == 0) { ssum[t >> 6] = sum; ssq[t >> 6] = sq; }
    __syncthreads();
    if (t == 0) {
        float S = ssum[0] + ssum[1] + ssum[2] + ssum[3];
        float Qq = ssq[0] + ssq[1] + ssq[2] + ssq[3];
        float mu = S / D_MODEL;
        s_mu = mu;
        s_rs = rsqrtf(Qq / D_MODEL - mu * mu + 1e-5f);
    }
    __syncthreads();
    const float mu = s_mu, rs = s_rs;
#pragma unroll
    for (int it = 0; it < 3; ++it) {
        int i = t + it * 256;
        out[base + i] = (bf16_t)((vals[it] - mu) * rs * g[i] + be[i]);
    }
}

__global__ __launch_bounds__(256) void ln_res_final_kernel(
    const bf16_t* __restrict__ a, const bf16_t* __restrict__ bfb,
    const float* __restrict__ g, const float* __restrict__ be,
    float* __restrict__ out) {
    const int row = blockIdx.x, t = threadIdx.x;
    const size_t base = (size_t)row * D_MODEL;
    float vals[3], sum = 0.f, sq = 0.f;
#pragma unroll
    for (int it = 0; it < 3; ++it) {
        int i = t + it * 256;
        float v = (float)a[base + i] + (float)bfb[base + i];
        vals[it] = v; sum += v; sq += v * v;
    }
#pragma unroll
    for (int d = 1; d < 64; d <<= 1) { sum += __shfl_xor(sum, d, 64); sq += __shfl_xor(sq, d, 64); }
    __shared__ float ssum[4], ssq[4], s_mu, s_rs;
    if ((t & 63) == 0) { ssum[t >> 6] = sum; ssq[t >> 6] = sq; }
    __syncthreads();
    if (t == 0) {
        float S = ssum[0] + ssum[1] + ssum[2] + ssum[3];
        float Qq = ssq[0] + ssq[1] + ssq[2] + ssq[3];
        float mu = S / D_MODEL;
        s_mu = mu;
        s_rs = rsqrtf(Qq / D_MODEL - mu * mu + 1e-5f);
    }
    __syncthreads();
    const float mu = s_mu, rs = s_rs;
#pragma unroll
    for (int it = 0; it < 3; ++it) {
        int i = t + it * 256;
        out[base + i] = (vals[it] - mu) * rs * g[i] + be[i];
    }
}

// ------------------------------- launcher ----------------------------------
extern "C" void kernel_launch(void* const* d_in, const int* in_sizes, int n_in,
                              void* d_out, int out_size, void* d_ws, size_t ws_size,
                              hipStream_t stream) {
    const float* x    = (const float*)d_in[0];
    const float* wq   = (const float*)d_in[1];
    const float* bq   = (const float*)d_in[2];
    const float* wk   = (const float*)d_in[3];
    const float* bk   = (const float*)d_in[4];
    const float* wv   = (const float*)d_in[5];
    const float* bv   = (const float*)d_in[6];
    const float* wo   = (const float*)d_in[7];
    const float* bo   = (const float*)d_in[8];
    const float* w1   = (const float*)d_in[9];
    const float* b1   = (const float*)d_in[10];
    const float* w2   = (const float*)d_in[11];
    const float* b2   = (const float*)d_in[12];
    const float* g1   = (const float*)d_in[13];
    const float* be1  = (const float*)d_in[14];
    const float* g2   = (const float*)d_in[15];
    const float* be2  = (const float*)d_in[16];
    float* out = (float*)d_out;

    // ---- workspace layout (aliased; ~127.5 MB) ----
    char* ws = (char*)d_ws;
    const size_t SZ_XB   = (size_t)M_ROWS * D_MODEL * 2;
    const size_t SZ_QKV  = (size_t)M_ROWS * LDQKV * 2;
    const size_t SZ_CTX  = SZ_XB;
    const size_t SZ_H    = (size_t)M_ROWS * H_FF * 2;
    const size_t SZ_WQKV = (size_t)LDQKV * D_MODEL * 2;
    const size_t SZ_WO   = (size_t)D_MODEL * D_MODEL * 2;
    const size_t SZ_W1   = (size_t)H_FF * D_MODEL * 2;

    bf16_t* xb    = (bf16_t*)(ws);                    // also n1 after LN1
    bf16_t* qkvb  = (bf16_t*)(ws + SZ_XB);            // also mha out (reuse)
    bf16_t* ctxb  = (bf16_t*)(ws + SZ_XB + SZ_QKV);   // also ffn2 out (reuse)
    bf16_t* hb    = (bf16_t*)(ws + SZ_XB + SZ_QKV + SZ_CTX);
    char*   wsw   = ws + SZ_XB + SZ_QKV + SZ_CTX + SZ_H;
    bf16_t* wqkvb = (bf16_t*)(wsw);
    bf16_t* wob   = (bf16_t*)(wsw + SZ_WQKV);
    bf16_t* w1b   = (bf16_t*)(wsw + SZ_WQKV + SZ_WO);
    bf16_t* w2b   = (bf16_t*)(wsw + SZ_WQKV + SZ_WO + SZ_W1);
    float*  bqkv  = (float*)(wsw + SZ_WQKV + SZ_WO + 2 * SZ_W1);
    bf16_t* mhab  = qkvb;
    bf16_t* n1b   = xb;
    bf16_t* ffb   = ctxb;

    const int n_x = M_ROWS * D_MODEL;
    const int n_w = D_MODEL * D_MODEL;
    const int n_wf = H_FF * D_MODEL;

    f32_to_bf16_scale_kernel<<<(n_x + 255) / 256, 256, 0, stream>>>(x, xb, n_x, 1.0f);
    f32_to_bf16_scale_kernel<<<(n_w + 255) / 256, 256, 0, stream>>>(wq, wqkvb, n_w, 0.125f);
    f32_to_bf16_scale_kernel<<<(n_w + 255) / 256, 256, 0, stream>>>(wk, wqkvb + (size_t)768 * 768, n_w, 1.0f);
    f32_to_bf16_scale_kernel<<<(n_w + 255) / 256, 256, 0, stream>>>(wv, wqkvb + (size_t)1536 * 768, n_w, 1.0f);
    f32_to_bf16_scale_kernel<<<(n_w + 255) / 256, 256, 0, stream>>>(wo, wob, n_w, 1.0f);
    f32_to_bf16_scale_kernel<<<(n_wf + 255) / 256, 256, 0, stream>>>(w1, w1b, n_wf, 1.0f);
    f32_to_bf16_scale_kernel<<<(n_wf + 255) / 256, 256, 0, stream>>>(w2, w2b, n_wf, 1.0f);
    pack_bias_kernel<<<9, 256, 0, stream>>>(bq, bk, bv, bqkv);

    gemm_lds_kernel<128><<<dim3(LDQKV / 128, M_ROWS / 128), 256, 0, stream>>>(
        xb, wqkvb, bqkv, qkvb, M_ROWS, LDQKV, D_MODEL, 0);

    attn_kernel<<<dim3(SEQ / 128, BATCH * N_HEADS), 256, 0, stream>>>(qkvb, ctxb);

    gemm_lds_kernel<64><<<dim3(D_MODEL / 64, M_ROWS / 128), 256, 0, stream>>>(
        ctxb, wob, bo, mhab, M_ROWS, D_MODEL, D_MODEL, 0);

    ln_res_f32in_kernel<<<M_ROWS, 256, 0, stream>>>(x, mhab, g1, be1, n1b);

    gemm_lds_kernel<128><<<dim3(H_FF / 128, M_ROWS / 128), 256, 0, stream>>>(
        n1b, w1b, b1, hb, M_ROWS, H_FF, D_MODEL, 1);

    gemm_lds_kernel<64><<<dim3(D_MODEL / 64, M_ROWS / 128), 256, 0, stream>>>(
        hb, w2b, b2, ffb, M_ROWS, D_MODEL, H_FF, 0);

    ln_res_final_kernel<<<M_ROWS, 256, 0, stream>>>(n1b, ffb, g2, be2, out);
}